// Round 7
// baseline (1182.758 us; speedup 1.0000x reference)
//
#include <hip/hip_runtime.h>
#include <hip/hip_bf16.h>

typedef __attribute__((ext_vector_type(8))) short short8;
typedef __attribute__((ext_vector_type(4))) float f32x4;

#define SEQ 8192
#define NBATCH 4
#define NT (SEQ / 32)

static __device__ __forceinline__ unsigned short f2bf(float f) {
    __hip_bfloat16 h = __float2bfloat16(f);
    unsigned short u;
    __builtin_memcpy(&u, &h, 2);
    return u;
}

static __device__ __forceinline__ int4 pack8(float4 a, float4 b) {
    union { unsigned short s[8]; int4 i; } r;
    r.s[0] = f2bf(a.x); r.s[1] = f2bf(a.y); r.s[2] = f2bf(a.z); r.s[3] = f2bf(a.w);
    r.s[4] = f2bf(b.x); r.s[5] = f2bf(b.y); r.s[6] = f2bf(b.z); r.s[7] = f2bf(b.w);
    return r.i;
}

// C[M][N] = A[M][256] * W[N][256]^T (+bias)*scale.  Tile 128x128, 4 waves.
// OMODE: 0 = bf16 row-major, 1 = f32 row-major, 2 = bf16 transposed per batch
// (out[(b*256+col)*8192 + s], for V^T). (structure verified rounds 2-6)
template<bool A_BF16, int OMODE>
__global__ __launch_bounds__(256) void proj_gemm(
    const void* __restrict__ Ap, const float* __restrict__ W,
    const float* __restrict__ bias, void* __restrict__ Outp, float scale)
{
    __shared__ alignas(16) unsigned short As[128][40];
    __shared__ alignas(16) unsigned short Bs[128][40];

    const int tid  = threadIdx.x;
    const int lane = tid & 63;
    const int wv   = tid >> 6;
    const int wm   = (wv >> 1) * 64, wn = (wv & 1) * 64;
    const int lr   = lane & 15, lg = lane >> 4;
    const int m0   = blockIdx.x * 128;
    const int n0   = blockIdx.y * 128;

    const int srow = tid >> 1;
    const int skc  = (tid & 1) * 16;

    f32x4 acc[4][4] = {};

    for (int k0 = 0; k0 < 256; k0 += 32) {
        __syncthreads();
        if (A_BF16) {
            const unsigned short* a = (const unsigned short*)Ap + (size_t)(m0 + srow) * 256 + k0 + skc;
            int4 v0 = *(const int4*)a;
            int4 v1 = *(const int4*)(a + 8);
            *(int4*)&As[srow][skc]     = v0;
            *(int4*)&As[srow][skc + 8] = v1;
        } else {
            const float* a = (const float*)Ap + (size_t)(m0 + srow) * 256 + k0 + skc;
            const float4* a4 = (const float4*)a;
            *(int4*)&As[srow][skc]     = pack8(a4[0], a4[1]);
            *(int4*)&As[srow][skc + 8] = pack8(a4[2], a4[3]);
        }
        {
            const float* b = W + (size_t)(n0 + srow) * 256 + k0 + skc;
            const float4* b4 = (const float4*)b;
            *(int4*)&Bs[srow][skc]     = pack8(b4[0], b4[1]);
            *(int4*)&Bs[srow][skc + 8] = pack8(b4[2], b4[3]);
        }
        __syncthreads();

        short8 af[4], bfr[4];
        #pragma unroll
        for (int fm = 0; fm < 4; ++fm)
            af[fm] = *(const short8*)&As[wm + fm * 16 + lr][lg * 8];
        #pragma unroll
        for (int fn = 0; fn < 4; ++fn)
            bfr[fn] = *(const short8*)&Bs[wn + fn * 16 + lr][lg * 8];
        #pragma unroll
        for (int fm = 0; fm < 4; ++fm)
            #pragma unroll
            for (int fn = 0; fn < 4; ++fn)
                acc[fm][fn] = __builtin_amdgcn_mfma_f32_16x16x32_bf16(
                    af[fm], bfr[fn], acc[fm][fn], 0, 0, 0);
    }

    float bvals[4];
    #pragma unroll
    for (int fn = 0; fn < 4; ++fn) bvals[fn] = bias[n0 + wn + fn * 16 + lr];

    #pragma unroll
    for (int fm = 0; fm < 4; ++fm) {
        #pragma unroll
        for (int fn = 0; fn < 4; ++fn) {
            #pragma unroll
            for (int r = 0; r < 4; ++r) {
                const int row = m0 + wm + fm * 16 + lg * 4 + r;
                const int col = n0 + wn + fn * 16 + lr;
                float val = (acc[fm][fn][r] + bvals[fn]) * scale;
                if (OMODE == 1) {
                    ((float*)Outp)[(size_t)row * 256 + col] = val;
                } else if (OMODE == 0) {
                    ((unsigned short*)Outp)[(size_t)row * 256 + col] = f2bf(val);
                } else {  // V^T: [b][d=col][s]
                    const int bb = row >> 13, s = row & 8191;
                    ((unsigned short*)Outp)[((size_t)(bb * 256 + col) << 13) + s] = f2bf(val);
                }
            }
        }
    }
}

// Flash attention, round 7.
// - NO K LDS: QK A-frags loaded directly from global (L2-resident; for fixed
//   lr the 4 lg-lanes cover a contiguous 64B line). Kills the 16 redundant
//   Ks b128 reads + 4 stage writes per wave-iter that dominated the LDS pipe.
// - V^T in global [b][d][S]: PV B-frags direct from global (round 6).
// - Per-iter: issue V loads, issue 16 K loads, QK (swapped, D[kv][q]),
//   per-lane softmax (log2 domain, defer-rescale THR=11), Ps write, ONE
//   barrier, PV. Ps/Cor/Flg double-buffered so barrier skew can't race.
__global__ __launch_bounds__(256) void attn_kernel(
    const unsigned short* __restrict__ Q, const unsigned short* __restrict__ K,
    const unsigned short* __restrict__ Vt, unsigned short* __restrict__ A)
{
    __shared__ alignas(16) unsigned short Ps[2][4][16][40]; // [buf][qt][q][kv]
    __shared__ alignas(16) float Cor[2][4][16];
    __shared__ alignas(16) float Ls[4][16];
    __shared__ int Flg[2][4];

    const int tid  = threadIdx.x;
    const int lane = tid & 63;
    const int wv   = tid >> 6;
    const int lr   = lane & 15, lg = lane >> 4;
    const int b    = blockIdx.y;
    const size_t qblk = (size_t)b * SEQ + blockIdx.x * 64;

    // Q frags (B-operand): wave wv owns q-tile wv
    short8 aq[8];
    #pragma unroll
    for (int c = 0; c < 8; ++c)
        aq[c] = *(const short8*)&Q[(qblk + wv * 16 + lr) * 256 + c * 32 + lg * 8];

    float m_run = -1e30f, l_run = 0.f;   // per-lane: q-row = lr (log2 domain)
    f32x4 o[4][4] = {};   // [qt][dt]: rows qt*16+lg*4+r, cols wv*64+dt*16+lr

    const unsigned short* Kb = K + (size_t)b * SEQ * 256;
    const unsigned short* Vb = Vt + ((size_t)b * 256 << 13);
    size_t vrow[4];
    #pragma unroll
    for (int dt = 0; dt < 4; ++dt)
        vrow[dt] = (size_t)(wv * 64 + dt * 16 + lr) << 13;
    // per-lane K row bases (elements)
    const size_t krow0 = (size_t)lr * 256 + lg * 8;
    const size_t krow1 = (size_t)(16 + lr) * 256 + lg * 8;

    for (int it = 0; it < NT; ++it) {
        const int p = it & 1;
        const unsigned short* Kt = Kb + (size_t)it * 32 * 256;

        // V^T frags for this tile's PV — issue first (longest slack)
        short8 vbr[4];
        const size_t kvp = (size_t)it * 32 + lg * 8;
        #pragma unroll
        for (int dt = 0; dt < 4; ++dt)
            vbr[dt] = *(const short8*)&Vb[vrow[dt] + kvp];

        // K frags direct from global, issue in consumption order
        short8 kf0[8], kf1[8];
        #pragma unroll
        for (int c = 0; c < 8; ++c) {
            kf0[c] = *(const short8*)&Kt[krow0 + c * 32];
            kf1[c] = *(const short8*)&Kt[krow1 + c * 32];
        }

        // Swapped QK^T: D[kv][q]. s0 = kv 0..15, s1 = kv 16..31
        f32x4 s0 = {}, s1 = {};
        #pragma unroll
        for (int c = 0; c < 8; ++c) {
            s0 = __builtin_amdgcn_mfma_f32_16x16x32_bf16(kf0[c], aq[c], s0, 0, 0, 0);
            s1 = __builtin_amdgcn_mfma_f32_16x16x32_bf16(kf1[c], aq[c], s1, 0, 0, 0);
        }

        // online softmax for q=lr (log2 domain), defer-rescale THR=11
        float mx = fmaxf(fmaxf(fmaxf(s0[0], s0[1]), fmaxf(s0[2], s0[3])),
                         fmaxf(fmaxf(s1[0], s1[1]), fmaxf(s1[2], s1[3])));
        mx = fmaxf(mx, __shfl_xor(mx, 16, 64));
        mx = fmaxf(mx, __shfl_xor(mx, 32, 64));

        const int need = __any(mx > m_run + 11.0f);
        float corr = 1.f;
        if (need) {
            float mnew = fmaxf(m_run, mx);
            corr = exp2f(m_run - mnew);
            m_run = mnew;
            if (lane < 16) Cor[p][wv][lr] = corr;
        }
        if (lane == 0) Flg[p][wv] = need;

        float p0[4], p1[4];
        #pragma unroll
        for (int r = 0; r < 4; ++r) {
            p0[r] = exp2f(s0[r] - m_run);
            p1[r] = exp2f(s1[r] - m_run);
        }
        float rs = ((p0[0] + p0[1]) + (p0[2] + p0[3])) +
                   ((p1[0] + p1[1]) + (p1[2] + p1[3]));
        rs += __shfl_xor(rs, 16, 64);
        rs += __shfl_xor(rs, 32, 64);
        l_run = (need ? l_run * corr : l_run) + rs;

        {   // pack P -> Ps[p] (kv-contiguous per lane), 2x b64
            unsigned int w0 = (unsigned)f2bf(p0[0]) | ((unsigned)f2bf(p0[1]) << 16);
            unsigned int w1 = (unsigned)f2bf(p0[2]) | ((unsigned)f2bf(p0[3]) << 16);
            unsigned int w2 = (unsigned)f2bf(p1[0]) | ((unsigned)f2bf(p1[1]) << 16);
            unsigned int w3 = (unsigned)f2bf(p1[2]) | ((unsigned)f2bf(p1[3]) << 16);
            *(unsigned long long*)&Ps[p][wv][lr][4 * lg] =
                (unsigned long long)w0 | ((unsigned long long)w1 << 32);
            *(unsigned long long*)&Ps[p][wv][lr][16 + 4 * lg] =
                (unsigned long long)w2 | ((unsigned long long)w3 << 32);
        }
        __syncthreads();   // Ps/Cor/Flg[p] visible to all waves

        // PV for own d-slice, all 4 q-tiles
        short8 pa[4];
        #pragma unroll
        for (int qt = 0; qt < 4; ++qt)
            pa[qt] = *(const short8*)&Ps[p][qt][lr][lg * 8];
        #pragma unroll
        for (int qt = 0; qt < 4; ++qt) {
            if (Flg[p][qt]) {
                float4 c4 = *(const float4*)&Cor[p][qt][lg * 4];
                #pragma unroll
                for (int dt = 0; dt < 4; ++dt) {
                    o[qt][dt][0] *= c4.x; o[qt][dt][1] *= c4.y;
                    o[qt][dt][2] *= c4.z; o[qt][dt][3] *= c4.w;
                }
            }
            #pragma unroll
            for (int dt = 0; dt < 4; ++dt)
                o[qt][dt] = __builtin_amdgcn_mfma_f32_16x16x32_bf16(pa[qt], vbr[dt], o[qt][dt], 0, 0, 0);
        }
    }

    // broadcast l, normalize, write
    if (lane < 16) Ls[wv][lr] = l_run;
    __syncthreads();
    #pragma unroll
    for (int qt = 0; qt < 4; ++qt) {
        float4 l4 = *(const float4*)&Ls[qt][lg * 4];
        float inv[4] = {1.f / l4.x, 1.f / l4.y, 1.f / l4.z, 1.f / l4.w};
        #pragma unroll
        for (int dt = 0; dt < 4; ++dt)
            #pragma unroll
            for (int r = 0; r < 4; ++r)
                A[(qblk + qt * 16 + lg * 4 + r) * 256 + wv * 64 + dt * 16 + lr] =
                    f2bf(o[qt][dt][r] * inv[r]);
    }
}

extern "C" void kernel_launch(void* const* d_in, const int* in_sizes, int n_in,
                              void* d_out, int out_size, void* d_ws, size_t ws_size,
                              hipStream_t stream) {
    (void)in_sizes; (void)n_in; (void)out_size; (void)ws_size;
    const float* x  = (const float*)d_in[0];
    const float* Wq = (const float*)d_in[1];
    const float* bq = (const float*)d_in[2];
    const float* Wk = (const float*)d_in[3];
    const float* bk = (const float*)d_in[4];
    const float* Wv = (const float*)d_in[5];
    const float* bv = (const float*)d_in[6];
    const float* Wo = (const float*)d_in[7];
    const float* bo = (const float*)d_in[8];
    float* out = (float*)d_out;

    char* ws = (char*)d_ws;
    const size_t MB16 = (size_t)16 * 1024 * 1024;
    unsigned short* qb = (unsigned short*)(ws);
    unsigned short* kb = (unsigned short*)(ws + MB16);
    unsigned short* vt = (unsigned short*)(ws + 2 * MB16);  // V^T [b][d][S]
    unsigned short* ab = (unsigned short*)(ws + 3 * MB16);

    dim3 gg(256, 2), bb(256);
    // scores in log2 domain: Q scale = d^-0.5 * log2(e)
    proj_gemm<false, 0><<<gg, bb, 0, stream>>>(x, Wq, bq, qb, 0.0625f * 1.44269504f);
    proj_gemm<false, 0><<<gg, bb, 0, stream>>>(x, Wk, bk, kb, 1.0f);
    proj_gemm<false, 2><<<gg, bb, 0, stream>>>(x, Wv, bv, vt, 1.0f);
    attn_kernel<<<dim3(128, NBATCH), bb, 0, stream>>>(qb, kb, vt, ab);
    proj_gemm<true, 1><<<gg, bb, 0, stream>>>(ab, Wo, bo, out, 1.0f);
}

// Round 8
// 676.813 us; speedup vs baseline: 1.7475x; 1.7475x over previous
//
#include <hip/hip_runtime.h>
#include <hip/hip_bf16.h>

typedef __attribute__((ext_vector_type(8))) short short8;
typedef __attribute__((ext_vector_type(4))) float f32x4;

#define SEQ 8192
#define NBATCH 4
#define NT (SEQ / 32)

static __device__ __forceinline__ unsigned short f2bf(float f) {
    __hip_bfloat16 h = __float2bfloat16(f);
    unsigned short u;
    __builtin_memcpy(&u, &h, 2);
    return u;
}

static __device__ __forceinline__ int4 pack8(float4 a, float4 b) {
    union { unsigned short s[8]; int4 i; } r;
    r.s[0] = f2bf(a.x); r.s[1] = f2bf(a.y); r.s[2] = f2bf(a.z); r.s[3] = f2bf(a.w);
    r.s[4] = f2bf(b.x); r.s[5] = f2bf(b.y); r.s[6] = f2bf(b.z); r.s[7] = f2bf(b.w);
    return r.i;
}

// C[M][N] = A[M][256] * W[N][256]^T (+bias)*scale.  Tile 128x128, 4 waves.
// OMODE: 0 = bf16 row-major, 1 = f32 row-major, 2 = bf16 transposed per batch
// (out[(b*256+col)*8192 + s], for V^T). (verified rounds 2-6)
template<bool A_BF16, int OMODE>
__global__ __launch_bounds__(256) void proj_gemm(
    const void* __restrict__ Ap, const float* __restrict__ W,
    const float* __restrict__ bias, void* __restrict__ Outp, float scale)
{
    __shared__ alignas(16) unsigned short As[128][40];
    __shared__ alignas(16) unsigned short Bs[128][40];

    const int tid  = threadIdx.x;
    const int lane = tid & 63;
    const int wv   = tid >> 6;
    const int wm   = (wv >> 1) * 64, wn = (wv & 1) * 64;
    const int lr   = lane & 15, lg = lane >> 4;
    const int m0   = blockIdx.x * 128;
    const int n0   = blockIdx.y * 128;

    const int srow = tid >> 1;
    const int skc  = (tid & 1) * 16;

    f32x4 acc[4][4] = {};

    for (int k0 = 0; k0 < 256; k0 += 32) {
        __syncthreads();
        if (A_BF16) {
            const unsigned short* a = (const unsigned short*)Ap + (size_t)(m0 + srow) * 256 + k0 + skc;
            int4 v0 = *(const int4*)a;
            int4 v1 = *(const int4*)(a + 8);
            *(int4*)&As[srow][skc]     = v0;
            *(int4*)&As[srow][skc + 8] = v1;
        } else {
            const float* a = (const float*)Ap + (size_t)(m0 + srow) * 256 + k0 + skc;
            const float4* a4 = (const float4*)a;
            *(int4*)&As[srow][skc]     = pack8(a4[0], a4[1]);
            *(int4*)&As[srow][skc + 8] = pack8(a4[2], a4[3]);
        }
        {
            const float* b = W + (size_t)(n0 + srow) * 256 + k0 + skc;
            const float4* b4 = (const float4*)b;
            *(int4*)&Bs[srow][skc]     = pack8(b4[0], b4[1]);
            *(int4*)&Bs[srow][skc + 8] = pack8(b4[2], b4[3]);
        }
        __syncthreads();

        short8 af[4], bfr[4];
        #pragma unroll
        for (int fm = 0; fm < 4; ++fm)
            af[fm] = *(const short8*)&As[wm + fm * 16 + lr][lg * 8];
        #pragma unroll
        for (int fn = 0; fn < 4; ++fn)
            bfr[fn] = *(const short8*)&Bs[wn + fn * 16 + lr][lg * 8];
        #pragma unroll
        for (int fm = 0; fm < 4; ++fm)
            #pragma unroll
            for (int fn = 0; fn < 4; ++fn)
                acc[fm][fn] = __builtin_amdgcn_mfma_f32_16x16x32_bf16(
                    af[fm], bfr[fn], acc[fm][fn], 0, 0, 0);
    }

    float bvals[4];
    #pragma unroll
    for (int fn = 0; fn < 4; ++fn) bvals[fn] = bias[n0 + wn + fn * 16 + lr];

    #pragma unroll
    for (int fm = 0; fm < 4; ++fm) {
        #pragma unroll
        for (int fn = 0; fn < 4; ++fn) {
            #pragma unroll
            for (int r = 0; r < 4; ++r) {
                const int row = m0 + wm + fm * 16 + lg * 4 + r;
                const int col = n0 + wn + fn * 16 + lr;
                float val = (acc[fm][fn][r] + bvals[fn]) * scale;
                if (OMODE == 1) {
                    ((float*)Outp)[(size_t)row * 256 + col] = val;
                } else if (OMODE == 0) {
                    ((unsigned short*)Outp)[(size_t)row * 256 + col] = f2bf(val);
                } else {  // V^T: [b][d=col][s]
                    const int bb = row >> 13, s = row & 8191;
                    ((unsigned short*)Outp)[((size_t)(bb * 256 + col) << 13) + s] = f2bf(val);
                }
            }
        }
    }
}

// Flash attention, round 8.
// - q-block 128: 4 waves x 32 q (2 B-frags aq0/aq1). Each K-frag LDS read
//   feeds 2 MFMAs -> K-LDS reads and staging per unit work HALVED vs r6.
// - Grid 256 = 1 block/CU, 1 wave/SIMD: __launch_bounds__(256,1) -> VGPR
//   cap 512, fits o[8][4] (128) + aq (64) without spill.
// - PV lags one iter (Ps/Cor/Flg dbuf): PV(t-1) MFMAs are independent of
//   softmax(t) VALU chain -> compiler interleaves, hides the serial phase.
// - K in LDS (reverted from r7: L2-direct was latency-bound), V^T direct
//   from global (r6, verified), log2-domain softmax, defer-rescale THR=11.
__global__ __launch_bounds__(256, 1) void attn_kernel(
    const unsigned short* __restrict__ Q, const unsigned short* __restrict__ K,
    const unsigned short* __restrict__ Vt, unsigned short* __restrict__ A)
{
    __shared__ alignas(16) unsigned short Ks[2][32][264];   // [buf][kv][d], pad +8
    __shared__ alignas(16) unsigned short Ps[2][8][16][40]; // [buf][qt][q][kv]
    __shared__ alignas(16) float Cor[2][128];
    __shared__ alignas(16) float Ls[128];
    __shared__ int Flg[2][8];

    const int tid  = threadIdx.x;
    const int lane = tid & 63;
    const int wv   = tid >> 6;
    const int lr   = lane & 15, lg = lane >> 4;
    const int b    = blockIdx.y;
    const size_t qblk = (size_t)b * SEQ + blockIdx.x * 128;

    // Q frags (B-operand): wave wv owns q rows wv*32..wv*32+31 (tiles 2wv, 2wv+1)
    short8 aq0[8], aq1[8];
    #pragma unroll
    for (int c = 0; c < 8; ++c) {
        aq0[c] = *(const short8*)&Q[(qblk + wv * 32 + lr) * 256 + c * 32 + lg * 8];
        aq1[c] = *(const short8*)&Q[(qblk + wv * 32 + 16 + lr) * 256 + c * 32 + lg * 8];
    }

    float m0 = -1e30f, l0 = 0.f;   // qsub0 (tile 2wv),   q = lr
    float m1 = -1e30f, l1 = 0.f;   // qsub1 (tile 2wv+1), q = lr
    f32x4 o[8][4] = {};            // [qt][dt]: rows qt*16+lg*4+r, cols wv*64+dt*16+lr

    const int krow = tid >> 3, kcol = (tid & 7) * 32;   // K staging map
    const unsigned short* Kb = K + (size_t)b * SEQ * 256;
    const unsigned short* Vb = Vt + ((size_t)b * 256 << 13);
    size_t vrow[4];
    #pragma unroll
    for (int dt = 0; dt < 4; ++dt)
        vrow[dt] = (size_t)(wv * 64 + dt * 16 + lr) << 13;

    // prologue: stage K(0) into Ks[0]
    {
        const int4* src = (const int4*)&Kb[(size_t)krow * 256 + kcol];
        int4 x0 = src[0], x1 = src[1], x2 = src[2], x3 = src[3];
        *(int4*)&Ks[0][krow][kcol]      = x0;
        *(int4*)&Ks[0][krow][kcol + 8]  = x1;
        *(int4*)&Ks[0][krow][kcol + 16] = x2;
        *(int4*)&Ks[0][krow][kcol + 24] = x3;
    }
    __syncthreads();

    for (int t = 0; t < NT; ++t) {
        const int p = t & 1;
        const bool have = (t + 1 < NT);

        // issue K(t+1) global loads early
        int4 x0, x1, x2, x3;
        if (have) {
            const int4* src = (const int4*)&Kb[((size_t)(t + 1) * 32 + krow) * 256 + kcol];
            x0 = src[0]; x1 = src[1]; x2 = src[2]; x3 = src[3];
        }
        // V^T frags for PV(t-1), direct from global (L2-resident)
        short8 vbr[4];
        if (t > 0) {
            const size_t kvp = (size_t)(t - 1) * 32 + lg * 8;
            #pragma unroll
            for (int dt = 0; dt < 4; ++dt)
                vbr[dt] = *(const short8*)&Vb[vrow[dt] + kvp];
        }

        // QK(t) from Ks[p] (swapped): each kb frag feeds BOTH q-subtiles
        f32x4 s00 = {}, s01 = {}, s10 = {}, s11 = {};
        #pragma unroll
        for (int c = 0; c < 8; ++c) {
            short8 kb0 = *(const short8*)&Ks[p][lr][c * 32 + lg * 8];
            short8 kb1 = *(const short8*)&Ks[p][16 + lr][c * 32 + lg * 8];
            s00 = __builtin_amdgcn_mfma_f32_16x16x32_bf16(kb0, aq0[c], s00, 0, 0, 0);
            s01 = __builtin_amdgcn_mfma_f32_16x16x32_bf16(kb1, aq0[c], s01, 0, 0, 0);
            s10 = __builtin_amdgcn_mfma_f32_16x16x32_bf16(kb0, aq1[c], s10, 0, 0, 0);
            s11 = __builtin_amdgcn_mfma_f32_16x16x32_bf16(kb1, aq1[c], s11, 0, 0, 0);
        }

        // PV(t-1): independent of softmax(t) -> interleaves with it
        if (t > 0) {
            const int q = p ^ 1;
            short8 pa[8];
            #pragma unroll
            for (int qt = 0; qt < 8; ++qt)
                pa[qt] = *(const short8*)&Ps[q][qt][lr][lg * 8];
            #pragma unroll
            for (int qt = 0; qt < 8; ++qt) {
                if (Flg[q][qt]) {
                    float4 c4 = *(const float4*)&Cor[q][qt * 16 + lg * 4];
                    #pragma unroll
                    for (int dt = 0; dt < 4; ++dt) {
                        o[qt][dt][0] *= c4.x; o[qt][dt][1] *= c4.y;
                        o[qt][dt][2] *= c4.z; o[qt][dt][3] *= c4.w;
                    }
                }
                #pragma unroll
                for (int dt = 0; dt < 4; ++dt)
                    o[qt][dt] = __builtin_amdgcn_mfma_f32_16x16x32_bf16(pa[qt], vbr[dt], o[qt][dt], 0, 0, 0);
            }
        }

        // softmax(t) for both q-subtiles (log2 domain), defer-rescale THR=11
        float mx0 = fmaxf(fmaxf(fmaxf(s00[0], s00[1]), fmaxf(s00[2], s00[3])),
                          fmaxf(fmaxf(s01[0], s01[1]), fmaxf(s01[2], s01[3])));
        float mx1 = fmaxf(fmaxf(fmaxf(s10[0], s10[1]), fmaxf(s10[2], s10[3])),
                          fmaxf(fmaxf(s11[0], s11[1]), fmaxf(s11[2], s11[3])));
        mx0 = fmaxf(mx0, __shfl_xor(mx0, 16, 64));
        mx0 = fmaxf(mx0, __shfl_xor(mx0, 32, 64));
        mx1 = fmaxf(mx1, __shfl_xor(mx1, 16, 64));
        mx1 = fmaxf(mx1, __shfl_xor(mx1, 32, 64));

        const int need = __any((mx0 > m0 + 11.0f) || (mx1 > m1 + 11.0f));
        if (need) {
            float n0 = fmaxf(m0, mx0), n1 = fmaxf(m1, mx1);
            float c0 = exp2f(m0 - n0), c1 = exp2f(m1 - n1);
            m0 = n0; m1 = n1;
            if (lane < 16) {
                Cor[p][wv * 32 + lr]      = c0;
                Cor[p][wv * 32 + 16 + lr] = c1;
            }
            if (need) { l0 *= c0; l1 *= c1; }
        }
        if (lane == 0) { Flg[p][2 * wv] = need; Flg[p][2 * wv + 1] = need; }

        float pa0[4], pb0[4], pa1[4], pb1[4];
        #pragma unroll
        for (int r = 0; r < 4; ++r) {
            pa0[r] = exp2f(s00[r] - m0);
            pb0[r] = exp2f(s01[r] - m0);
            pa1[r] = exp2f(s10[r] - m1);
            pb1[r] = exp2f(s11[r] - m1);
        }
        float rs0 = ((pa0[0] + pa0[1]) + (pa0[2] + pa0[3])) +
                    ((pb0[0] + pb0[1]) + (pb0[2] + pb0[3]));
        float rs1 = ((pa1[0] + pa1[1]) + (pa1[2] + pa1[3])) +
                    ((pb1[0] + pb1[1]) + (pb1[2] + pb1[3]));
        rs0 += __shfl_xor(rs0, 16, 64); rs0 += __shfl_xor(rs0, 32, 64);
        rs1 += __shfl_xor(rs1, 16, 64); rs1 += __shfl_xor(rs1, 32, 64);
        l0 += rs0; l1 += rs1;

        {   // pack P -> Ps[p] (kv-contiguous per lane), 4x b64
            unsigned int w0 = (unsigned)f2bf(pa0[0]) | ((unsigned)f2bf(pa0[1]) << 16);
            unsigned int w1 = (unsigned)f2bf(pa0[2]) | ((unsigned)f2bf(pa0[3]) << 16);
            unsigned int w2 = (unsigned)f2bf(pb0[0]) | ((unsigned)f2bf(pb0[1]) << 16);
            unsigned int w3 = (unsigned)f2bf(pb0[2]) | ((unsigned)f2bf(pb0[3]) << 16);
            *(unsigned long long*)&Ps[p][2 * wv][lr][4 * lg] =
                (unsigned long long)w0 | ((unsigned long long)w1 << 32);
            *(unsigned long long*)&Ps[p][2 * wv][lr][16 + 4 * lg] =
                (unsigned long long)w2 | ((unsigned long long)w3 << 32);
            unsigned int w4 = (unsigned)f2bf(pa1[0]) | ((unsigned)f2bf(pa1[1]) << 16);
            unsigned int w5 = (unsigned)f2bf(pa1[2]) | ((unsigned)f2bf(pa1[3]) << 16);
            unsigned int w6 = (unsigned)f2bf(pb1[0]) | ((unsigned)f2bf(pb1[1]) << 16);
            unsigned int w7 = (unsigned)f2bf(pb1[2]) | ((unsigned)f2bf(pb1[3]) << 16);
            *(unsigned long long*)&Ps[p][2 * wv + 1][lr][4 * lg] =
                (unsigned long long)w4 | ((unsigned long long)w5 << 32);
            *(unsigned long long*)&Ps[p][2 * wv + 1][lr][16 + 4 * lg] =
                (unsigned long long)w6 | ((unsigned long long)w7 << 32);
        }

        // write staged K(t+1) into the other buffer
        if (have) {
            *(int4*)&Ks[p ^ 1][krow][kcol]      = x0;
            *(int4*)&Ks[p ^ 1][krow][kcol + 8]  = x1;
            *(int4*)&Ks[p ^ 1][krow][kcol + 16] = x2;
            *(int4*)&Ks[p ^ 1][krow][kcol + 24] = x3;
        }
        __syncthreads();   // Ps/Cor/Flg[p] + Ks[p^1] visible
    }

    // epilogue: PV(NT-1) from Ps[(NT-1)&1]
    {
        const int q = (NT - 1) & 1;
        const size_t kvp = (size_t)(NT - 1) * 32 + lg * 8;
        short8 vbr[4];
        #pragma unroll
        for (int dt = 0; dt < 4; ++dt)
            vbr[dt] = *(const short8*)&Vb[vrow[dt] + kvp];
        short8 pa[8];
        #pragma unroll
        for (int qt = 0; qt < 8; ++qt)
            pa[qt] = *(const short8*)&Ps[q][qt][lr][lg * 8];
        #pragma unroll
        for (int qt = 0; qt < 8; ++qt) {
            if (Flg[q][qt]) {
                float4 c4 = *(const float4*)&Cor[q][qt * 16 + lg * 4];
                #pragma unroll
                for (int dt = 0; dt < 4; ++dt) {
                    o[qt][dt][0] *= c4.x; o[qt][dt][1] *= c4.y;
                    o[qt][dt][2] *= c4.z; o[qt][dt][3] *= c4.w;
                }
            }
            #pragma unroll
            for (int dt = 0; dt < 4; ++dt)
                o[qt][dt] = __builtin_amdgcn_mfma_f32_16x16x32_bf16(pa[qt], vbr[dt], o[qt][dt], 0, 0, 0);
        }
    }

    // broadcast l, normalize, write
    if (lane < 16) { Ls[wv * 32 + lr] = l0; Ls[wv * 32 + 16 + lr] = l1; }
    __syncthreads();
    #pragma unroll
    for (int qt = 0; qt < 8; ++qt) {
        float4 l4 = *(const float4*)&Ls[qt * 16 + lg * 4];
        float inv[4] = {1.f / l4.x, 1.f / l4.y, 1.f / l4.z, 1.f / l4.w};
        #pragma unroll
        for (int dt = 0; dt < 4; ++dt)
            #pragma unroll
            for (int r = 0; r < 4; ++r)
                A[(qblk + qt * 16 + lg * 4 + r) * 256 + wv * 64 + dt * 16 + lr] =
                    f2bf(o[qt][dt][r] * inv[r]);
    }
}

extern "C" void kernel_launch(void* const* d_in, const int* in_sizes, int n_in,
                              void* d_out, int out_size, void* d_ws, size_t ws_size,
                              hipStream_t stream) {
    (void)in_sizes; (void)n_in; (void)out_size; (void)ws_size;
    const float* x  = (const float*)d_in[0];
    const float* Wq = (const float*)d_in[1];
    const float* bq = (const float*)d_in[2];
    const float* Wk = (const float*)d_in[3];
    const float* bk = (const float*)d_in[4];
    const float* Wv = (const float*)d_in[5];
    const float* bv = (const float*)d_in[6];
    const float* Wo = (const float*)d_in[7];
    const float* bo = (const float*)d_in[8];
    float* out = (float*)d_out;

    char* ws = (char*)d_ws;
    const size_t MB16 = (size_t)16 * 1024 * 1024;
    unsigned short* qb = (unsigned short*)(ws);
    unsigned short* kb = (unsigned short*)(ws + MB16);
    unsigned short* vt = (unsigned short*)(ws + 2 * MB16);  // V^T [b][d][S]
    unsigned short* ab = (unsigned short*)(ws + 3 * MB16);

    dim3 gg(256, 2), bb(256);
    // scores in log2 domain: Q scale = d^-0.5 * log2(e)
    proj_gemm<false, 0><<<gg, bb, 0, stream>>>(x, Wq, bq, qb, 0.0625f * 1.44269504f);
    proj_gemm<false, 0><<<gg, bb, 0, stream>>>(x, Wk, bk, kb, 1.0f);
    proj_gemm<false, 2><<<gg, bb, 0, stream>>>(x, Wv, bv, vt, 1.0f);
    attn_kernel<<<dim3(64, NBATCH), bb, 0, stream>>>(qb, kb, vt, ab);
    proj_gemm<true, 1><<<gg, bb, 0, stream>>>(ab, Wo, bo, out, 1.0f);
}

// Round 9
// 557.184 us; speedup vs baseline: 2.1227x; 1.2147x over previous
//
#include <hip/hip_runtime.h>
#include <hip/hip_bf16.h>

typedef __attribute__((ext_vector_type(8))) short short8;
typedef __attribute__((ext_vector_type(4))) float f32x4;

#define SEQ 8192
#define NBATCH 4
#define NT (SEQ / 32)

static __device__ __forceinline__ unsigned short f2bf(float f) {
    __hip_bfloat16 h = __float2bfloat16(f);
    unsigned short u;
    __builtin_memcpy(&u, &h, 2);
    return u;
}

static __device__ __forceinline__ int4 pack8(float4 a, float4 b) {
    union { unsigned short s[8]; int4 i; } r;
    r.s[0] = f2bf(a.x); r.s[1] = f2bf(a.y); r.s[2] = f2bf(a.z); r.s[3] = f2bf(a.w);
    r.s[4] = f2bf(b.x); r.s[5] = f2bf(b.y); r.s[6] = f2bf(b.z); r.s[7] = f2bf(b.w);
    return r.i;
}

// C[M][N] = A[M][256] * W[N][256]^T (+bias)*scale.  Tile 128x128, 4 waves.
// OMODE: 0 = bf16 row-major, 1 = f32 row-major, 2 = bf16 transposed per batch
// (out[(b*256+col)*8192 + s], for V^T). (verified rounds 2-6)
template<bool A_BF16, int OMODE>
__global__ __launch_bounds__(256) void proj_gemm(
    const void* __restrict__ Ap, const float* __restrict__ W,
    const float* __restrict__ bias, void* __restrict__ Outp, float scale)
{
    __shared__ alignas(16) unsigned short As[128][40];
    __shared__ alignas(16) unsigned short Bs[128][40];

    const int tid  = threadIdx.x;
    const int lane = tid & 63;
    const int wv   = tid >> 6;
    const int wm   = (wv >> 1) * 64, wn = (wv & 1) * 64;
    const int lr   = lane & 15, lg = lane >> 4;
    const int m0   = blockIdx.x * 128;
    const int n0   = blockIdx.y * 128;

    const int srow = tid >> 1;
    const int skc  = (tid & 1) * 16;

    f32x4 acc[4][4] = {};

    for (int k0 = 0; k0 < 256; k0 += 32) {
        __syncthreads();
        if (A_BF16) {
            const unsigned short* a = (const unsigned short*)Ap + (size_t)(m0 + srow) * 256 + k0 + skc;
            int4 v0 = *(const int4*)a;
            int4 v1 = *(const int4*)(a + 8);
            *(int4*)&As[srow][skc]     = v0;
            *(int4*)&As[srow][skc + 8] = v1;
        } else {
            const float* a = (const float*)Ap + (size_t)(m0 + srow) * 256 + k0 + skc;
            const float4* a4 = (const float4*)a;
            *(int4*)&As[srow][skc]     = pack8(a4[0], a4[1]);
            *(int4*)&As[srow][skc + 8] = pack8(a4[2], a4[3]);
        }
        {
            const float* b = W + (size_t)(n0 + srow) * 256 + k0 + skc;
            const float4* b4 = (const float4*)b;
            *(int4*)&Bs[srow][skc]     = pack8(b4[0], b4[1]);
            *(int4*)&Bs[srow][skc + 8] = pack8(b4[2], b4[3]);
        }
        __syncthreads();

        short8 af[4], bfr[4];
        #pragma unroll
        for (int fm = 0; fm < 4; ++fm)
            af[fm] = *(const short8*)&As[wm + fm * 16 + lr][lg * 8];
        #pragma unroll
        for (int fn = 0; fn < 4; ++fn)
            bfr[fn] = *(const short8*)&Bs[wn + fn * 16 + lr][lg * 8];
        #pragma unroll
        for (int fm = 0; fm < 4; ++fm)
            #pragma unroll
            for (int fn = 0; fn < 4; ++fn)
                acc[fm][fn] = __builtin_amdgcn_mfma_f32_16x16x32_bf16(
                    af[fm], bfr[fn], acc[fm][fn], 0, 0, 0);
    }

    float bvals[4];
    #pragma unroll
    for (int fn = 0; fn < 4; ++fn) bvals[fn] = bias[n0 + wn + fn * 16 + lr];

    #pragma unroll
    for (int fm = 0; fm < 4; ++fm) {
        #pragma unroll
        for (int fn = 0; fn < 4; ++fn) {
            #pragma unroll
            for (int r = 0; r < 4; ++r) {
                const int row = m0 + wm + fm * 16 + lg * 4 + r;
                const int col = n0 + wn + fn * 16 + lr;
                float val = (acc[fm][fn][r] + bvals[fn]) * scale;
                if (OMODE == 1) {
                    ((float*)Outp)[(size_t)row * 256 + col] = val;
                } else if (OMODE == 0) {
                    ((unsigned short*)Outp)[(size_t)row * 256 + col] = f2bf(val);
                } else {  // V^T: [b][d=col][s]
                    const int bb = row >> 13, s = row & 8191;
                    ((unsigned short*)Outp)[((size_t)(bb * 256 + col) << 13) + s] = f2bf(val);
                }
            }
        }
    }
}

// Flash attention, round 9 = round 6 structure (best verified: 16q/wave,
// 4 waves, 512 blocks = 2 blocks/CU) with ONE change:
// - K staged via __builtin_amdgcn_global_load_lds (16B) into a pair-padded
//   linear layout: row r at byte (r>>1)*1040 + (r&1)*512 (16B pad per 1KB
//   row-pair). DMA writes are bank-sequential (zero conflicts, no VGPR
//   roundtrip); frag reads hit the 2-lanes/quad floor via the 1040B skew.
// - V^T direct from global, swapped QK, log2 softmax, defer-rescale THR=11,
//   PV lags via Ps/Cor/Flg double-buffer, one barrier/iter (all verified r6).
#define KROWOFF(r) (((r) >> 1) * 1040 + ((r) & 1) * 512)

__global__ __launch_bounds__(256) void attn_kernel(
    const unsigned short* __restrict__ Q, const unsigned short* __restrict__ K,
    const unsigned short* __restrict__ Vt, unsigned short* __restrict__ A)
{
    __shared__ alignas(16) char Ks[2][16640];               // pair-padded K tiles
    __shared__ alignas(16) unsigned short Ps[2][4][16][40]; // [buf][qt][q][kv]
    __shared__ alignas(16) float Cor[2][4][16];
    __shared__ alignas(16) float Ls[4][16];
    __shared__ int Flg[2][4];

    const int tid  = threadIdx.x;
    const int lane = tid & 63;
    const int wv   = tid >> 6;
    const int lr   = lane & 15, lg = lane >> 4;
    const int b    = blockIdx.y;
    const size_t qblk = (size_t)b * SEQ + blockIdx.x * 64;

    // Q frags (B-operand): wave wv owns q-tile wv
    short8 aq[8];
    #pragma unroll
    for (int c = 0; c < 8; ++c)
        aq[c] = *(const short8*)&Q[(qblk + wv * 16 + lr) * 256 + c * 32 + lg * 8];

    float m_run = -1e30f, l_run = 0.f;   // per-lane: q-row = lr (log2 domain)
    f32x4 o[4][4] = {};   // [qt][dt]: rows qt*16+lg*4+r, cols wv*64+dt*16+lr

    const unsigned short* Kb = K + (size_t)b * SEQ * 256;
    const unsigned short* Vb = Vt + ((size_t)b * 256 << 13);
    size_t vrow[4];
    #pragma unroll
    for (int dt = 0; dt < 4; ++dt)
        vrow[dt] = (size_t)(wv * 64 + dt * 16 + lr) << 13;

    // K staging: wave wv stages row-pairs 4wv..4wv+3 (rows 8wv..8wv+7).
    // gload_lds: per inst, lane l writes dst_base + l*16 (rows 2p, 2p+1).
    const int srow = lane >> 5;           // row within pair (src addressing)
    const int scol = (lane & 31) * 8;     // src col elements
    // K frag read bases (per lane): row lr and row 16+lr, k-sub lg
    const int kb_base = KROWOFF(lr) + lg * 16;   // + c*64; row 16+lr = +8320

    // prologue: stage tile 0 into Ks[0]
    #pragma unroll
    for (int i = 0; i < 4; ++i) {
        const int pr = 4 * wv + i;
        const unsigned short* src = Kb + (size_t)(2 * pr + srow) * 256 + scol;
        __builtin_amdgcn_global_load_lds(
            (const __attribute__((address_space(1))) void*)src,
            (__attribute__((address_space(3))) void*)&Ks[0][pr * 1040], 16, 0, 0);
    }
    __syncthreads();

    for (int t = 0; t < NT; ++t) {
        const int p = t & 1;

        // issue K(t+1) DMA into the other buffer (drains at the barrier)
        if (t + 1 < NT) {
            #pragma unroll
            for (int i = 0; i < 4; ++i) {
                const int pr = 4 * wv + i;
                const unsigned short* src =
                    Kb + ((size_t)(t + 1) * 32 + 2 * pr + srow) * 256 + scol;
                __builtin_amdgcn_global_load_lds(
                    (const __attribute__((address_space(1))) void*)src,
                    (__attribute__((address_space(3))) void*)&Ks[p ^ 1][pr * 1040], 16, 0, 0);
            }
        }

        // V^T frags for PV(t-1), direct from global (L2-resident)
        short8 vbr[4];
        if (t > 0) {
            const size_t kvp = (size_t)(t - 1) * 32 + lg * 8;
            #pragma unroll
            for (int dt = 0; dt < 4; ++dt)
                vbr[dt] = *(const short8*)&Vb[vrow[dt] + kvp];
        }

        // QK(t) from Ks[p] (swapped): s0 = kv 0..15, s1 = kv 16..31
        f32x4 s0 = {}, s1 = {};
        #pragma unroll
        for (int c = 0; c < 8; ++c) {
            short8 kb0 = *(const short8*)&Ks[p][kb_base + c * 64];
            short8 kb1 = *(const short8*)&Ks[p][kb_base + 8320 + c * 64];
            s0 = __builtin_amdgcn_mfma_f32_16x16x32_bf16(kb0, aq[c], s0, 0, 0, 0);
            s1 = __builtin_amdgcn_mfma_f32_16x16x32_bf16(kb1, aq[c], s1, 0, 0, 0);
        }

        // online softmax for q=lr (log2 domain), defer-rescale THR=11
        float mx = fmaxf(fmaxf(fmaxf(s0[0], s0[1]), fmaxf(s0[2], s0[3])),
                         fmaxf(fmaxf(s1[0], s1[1]), fmaxf(s1[2], s1[3])));
        mx = fmaxf(mx, __shfl_xor(mx, 16, 64));
        mx = fmaxf(mx, __shfl_xor(mx, 32, 64));

        const int need = __any(mx > m_run + 11.0f);
        float corr = 1.f;
        if (need) {
            float mnew = fmaxf(m_run, mx);
            corr = exp2f(m_run - mnew);
            m_run = mnew;
            if (lane < 16) Cor[p ^ 1][wv][lr] = corr;
        }
        if (lane == 0) Flg[p ^ 1][wv] = need;

        float p0[4], p1[4];
        #pragma unroll
        for (int r = 0; r < 4; ++r) {
            p0[r] = exp2f(s0[r] - m_run);
            p1[r] = exp2f(s1[r] - m_run);
        }
        float rs = ((p0[0] + p0[1]) + (p0[2] + p0[3])) +
                   ((p1[0] + p1[1]) + (p1[2] + p1[3]));
        rs += __shfl_xor(rs, 16, 64);
        rs += __shfl_xor(rs, 32, 64);
        l_run = (need ? l_run * corr : l_run) + rs;

        {   // pack P -> Ps[p^1] (kv-contiguous per lane), 2x b64
            unsigned int w0 = (unsigned)f2bf(p0[0]) | ((unsigned)f2bf(p0[1]) << 16);
            unsigned int w1 = (unsigned)f2bf(p0[2]) | ((unsigned)f2bf(p0[3]) << 16);
            unsigned int w2 = (unsigned)f2bf(p1[0]) | ((unsigned)f2bf(p1[1]) << 16);
            unsigned int w3 = (unsigned)f2bf(p1[2]) | ((unsigned)f2bf(p1[3]) << 16);
            *(unsigned long long*)&Ps[p ^ 1][wv][lr][4 * lg] =
                (unsigned long long)w0 | ((unsigned long long)w1 << 32);
            *(unsigned long long*)&Ps[p ^ 1][wv][lr][16 + 4 * lg] =
                (unsigned long long)w2 | ((unsigned long long)w3 << 32);
        }

        // PV(t-1): P from Ps[p], rescale via Flg/Cor[p], V frags from global
        if (t > 0) {
            short8 pa[4];
            #pragma unroll
            for (int qt = 0; qt < 4; ++qt)
                pa[qt] = *(const short8*)&Ps[p][qt][lr][lg * 8];
            #pragma unroll
            for (int qt = 0; qt < 4; ++qt) {
                if (Flg[p][qt]) {
                    float4 c4 = *(const float4*)&Cor[p][qt][lg * 4];
                    #pragma unroll
                    for (int dt = 0; dt < 4; ++dt) {
                        o[qt][dt][0] *= c4.x; o[qt][dt][1] *= c4.y;
                        o[qt][dt][2] *= c4.z; o[qt][dt][3] *= c4.w;
                    }
                }
                #pragma unroll
                for (int dt = 0; dt < 4; ++dt)
                    o[qt][dt] = __builtin_amdgcn_mfma_f32_16x16x32_bf16(pa[qt], vbr[dt], o[qt][dt], 0, 0, 0);
            }
        }
        __syncthreads();   // Ks[p^1] DMA drained; Ps/Cor/Flg[p^1] visible
    }

    // epilogue: PV(NT-1) from Ps[NT&1]
    {
        const int p = NT & 1;
        const size_t kvp = (size_t)(NT - 1) * 32 + lg * 8;
        short8 vbr[4];
        #pragma unroll
        for (int dt = 0; dt < 4; ++dt)
            vbr[dt] = *(const short8*)&Vb[vrow[dt] + kvp];
        short8 pa[4];
        #pragma unroll
        for (int qt = 0; qt < 4; ++qt)
            pa[qt] = *(const short8*)&Ps[p][qt][lr][lg * 8];
        #pragma unroll
        for (int qt = 0; qt < 4; ++qt) {
            if (Flg[p][qt]) {
                float4 c4 = *(const float4*)&Cor[p][qt][lg * 4];
                #pragma unroll
                for (int dt = 0; dt < 4; ++dt) {
                    o[qt][dt][0] *= c4.x; o[qt][dt][1] *= c4.y;
                    o[qt][dt][2] *= c4.z; o[qt][dt][3] *= c4.w;
                }
            }
            #pragma unroll
            for (int dt = 0; dt < 4; ++dt)
                o[qt][dt] = __builtin_amdgcn_mfma_f32_16x16x32_bf16(pa[qt], vbr[dt], o[qt][dt], 0, 0, 0);
        }
    }

    // broadcast l, normalize, write
    if (lane < 16) Ls[wv][lr] = l_run;
    __syncthreads();
    #pragma unroll
    for (int qt = 0; qt < 4; ++qt) {
        float4 l4 = *(const float4*)&Ls[qt][lg * 4];
        float inv[4] = {1.f / l4.x, 1.f / l4.y, 1.f / l4.z, 1.f / l4.w};
        #pragma unroll
        for (int dt = 0; dt < 4; ++dt)
            #pragma unroll
            for (int r = 0; r < 4; ++r)
                A[(qblk + qt * 16 + lg * 4 + r) * 256 + wv * 64 + dt * 16 + lr] =
                    f2bf(o[qt][dt][r] * inv[r]);
    }
}

extern "C" void kernel_launch(void* const* d_in, const int* in_sizes, int n_in,
                              void* d_out, int out_size, void* d_ws, size_t ws_size,
                              hipStream_t stream) {
    (void)in_sizes; (void)n_in; (void)out_size; (void)ws_size;
    const float* x  = (const float*)d_in[0];
    const float* Wq = (const float*)d_in[1];
    const float* bq = (const float*)d_in[2];
    const float* Wk = (const float*)d_in[3];
    const float* bk = (const float*)d_in[4];
    const float* Wv = (const float*)d_in[5];
    const float* bv = (const float*)d_in[6];
    const float* Wo = (const float*)d_in[7];
    const float* bo = (const float*)d_in[8];
    float* out = (float*)d_out;

    char* ws = (char*)d_ws;
    const size_t MB16 = (size_t)16 * 1024 * 1024;
    unsigned short* qb = (unsigned short*)(ws);
    unsigned short* kb = (unsigned short*)(ws + MB16);
    unsigned short* vt = (unsigned short*)(ws + 2 * MB16);  // V^T [b][d][S]
    unsigned short* ab = (unsigned short*)(ws + 3 * MB16);

    dim3 gg(256, 2), bb(256);
    // scores in log2 domain: Q scale = d^-0.5 * log2(e)
    proj_gemm<false, 0><<<gg, bb, 0, stream>>>(x, Wq, bq, qb, 0.0625f * 1.44269504f);
    proj_gemm<false, 0><<<gg, bb, 0, stream>>>(x, Wk, bk, kb, 1.0f);
    proj_gemm<false, 2><<<gg, bb, 0, stream>>>(x, Wv, bv, vt, 1.0f);
    attn_kernel<<<dim3(128, NBATCH), bb, 0, stream>>>(qb, kb, vt, ab);
    proj_gemm<true, 1><<<gg, bb, 0, stream>>>(ab, Wo, bo, out, 1.0f);
}

// Round 10
// 459.130 us; speedup vs baseline: 2.5761x; 1.2136x over previous
//
#include <hip/hip_runtime.h>
#include <hip/hip_bf16.h>

typedef __attribute__((ext_vector_type(8))) short short8;
typedef __attribute__((ext_vector_type(4))) float f32x4;

#define SEQ 8192
#define NBATCH 4
#define NT (SEQ / 32)

static __device__ __forceinline__ unsigned short f2bf(float f) {
    __hip_bfloat16 h = __float2bfloat16(f);
    unsigned short u;
    __builtin_memcpy(&u, &h, 2);
    return u;
}

static __device__ __forceinline__ int4 pack8(float4 a, float4 b) {
    union { unsigned short s[8]; int4 i; } r;
    r.s[0] = f2bf(a.x); r.s[1] = f2bf(a.y); r.s[2] = f2bf(a.z); r.s[3] = f2bf(a.w);
    r.s[4] = f2bf(b.x); r.s[5] = f2bf(b.y); r.s[6] = f2bf(b.z); r.s[7] = f2bf(b.w);
    return r.i;
}

// C[M][N] = A[M][256] * W[N][256]^T (+bias)*scale.  Tile 128x128, 4 waves.
// OMODE: 0 = bf16 row-major, 1 = f32 row-major, 2 = bf16 transposed per batch
// (out[(b*256+col)*8192 + s], for V^T). (verified rounds 2-6)
template<bool A_BF16, int OMODE>
__global__ __launch_bounds__(256) void proj_gemm(
    const void* __restrict__ Ap, const float* __restrict__ W,
    const float* __restrict__ bias, void* __restrict__ Outp, float scale)
{
    __shared__ alignas(16) unsigned short As[128][40];
    __shared__ alignas(16) unsigned short Bs[128][40];

    const int tid  = threadIdx.x;
    const int lane = tid & 63;
    const int wv   = tid >> 6;
    const int wm   = (wv >> 1) * 64, wn = (wv & 1) * 64;
    const int lr   = lane & 15, lg = lane >> 4;
    const int m0   = blockIdx.x * 128;
    const int n0   = blockIdx.y * 128;

    const int srow = tid >> 1;
    const int skc  = (tid & 1) * 16;

    f32x4 acc[4][4] = {};

    for (int k0 = 0; k0 < 256; k0 += 32) {
        __syncthreads();
        if (A_BF16) {
            const unsigned short* a = (const unsigned short*)Ap + (size_t)(m0 + srow) * 256 + k0 + skc;
            int4 v0 = *(const int4*)a;
            int4 v1 = *(const int4*)(a + 8);
            *(int4*)&As[srow][skc]     = v0;
            *(int4*)&As[srow][skc + 8] = v1;
        } else {
            const float* a = (const float*)Ap + (size_t)(m0 + srow) * 256 + k0 + skc;
            const float4* a4 = (const float4*)a;
            *(int4*)&As[srow][skc]     = pack8(a4[0], a4[1]);
            *(int4*)&As[srow][skc + 8] = pack8(a4[2], a4[3]);
        }
        {
            const float* b = W + (size_t)(n0 + srow) * 256 + k0 + skc;
            const float4* b4 = (const float4*)b;
            *(int4*)&Bs[srow][skc]     = pack8(b4[0], b4[1]);
            *(int4*)&Bs[srow][skc + 8] = pack8(b4[2], b4[3]);
        }
        __syncthreads();

        short8 af[4], bfr[4];
        #pragma unroll
        for (int fm = 0; fm < 4; ++fm)
            af[fm] = *(const short8*)&As[wm + fm * 16 + lr][lg * 8];
        #pragma unroll
        for (int fn = 0; fn < 4; ++fn)
            bfr[fn] = *(const short8*)&Bs[wn + fn * 16 + lr][lg * 8];
        #pragma unroll
        for (int fm = 0; fm < 4; ++fm)
            #pragma unroll
            for (int fn = 0; fn < 4; ++fn)
                acc[fm][fn] = __builtin_amdgcn_mfma_f32_16x16x32_bf16(
                    af[fm], bfr[fn], acc[fm][fn], 0, 0, 0);
    }

    float bvals[4];
    #pragma unroll
    for (int fn = 0; fn < 4; ++fn) bvals[fn] = bias[n0 + wn + fn * 16 + lr];

    #pragma unroll
    for (int fm = 0; fm < 4; ++fm) {
        #pragma unroll
        for (int fn = 0; fn < 4; ++fn) {
            #pragma unroll
            for (int r = 0; r < 4; ++r) {
                const int row = m0 + wm + fm * 16 + lg * 4 + r;
                const int col = n0 + wn + fn * 16 + lr;
                float val = (acc[fm][fn][r] + bvals[fn]) * scale;
                if (OMODE == 1) {
                    ((float*)Outp)[(size_t)row * 256 + col] = val;
                } else if (OMODE == 0) {
                    ((unsigned short*)Outp)[(size_t)row * 256 + col] = f2bf(val);
                } else {  // V^T: [b][d=col][s]
                    const int bb = row >> 13, s = row & 8191;
                    ((unsigned short*)Outp)[((size_t)(bb * 256 + col) << 13) + s] = f2bf(val);
                }
            }
        }
    }
}

// Flash attention, round 10 = round 6 (best verified) with ONE change:
// K-stage writes use a 128B-interleaved chunk map — thread (krow=tid>>3,
// ch=tid&7) writes 16B chunks at byte ch*16 + j*128 within its 528B row
// (was ch*64 + j*16). Write quad = ((tid>>3)+(tid&7))%8 -> 2 lanes/quad
// per 16-lane phase = conflict FLOOR (old map was 4-way). LDS content and
// frag reads are bit-identical to r6; only write order changes.
// Everything else verified r6: swapped QK (D[kv][q]), per-lane log2 softmax,
// defer-rescale THR=11, Ps/Cor/Flg dbuf, PV lags 1 iter, V^T direct from
// global, one barrier/iter.
__global__ __launch_bounds__(256) void attn_kernel(
    const unsigned short* __restrict__ Q, const unsigned short* __restrict__ K,
    const unsigned short* __restrict__ Vt, unsigned short* __restrict__ A)
{
    __shared__ alignas(16) unsigned short Ks[2][32][264];   // [buf][kv][d], pad +8
    __shared__ alignas(16) unsigned short Ps[2][4][16][40]; // [buf][qt][q][kv]
    __shared__ alignas(16) float Cor[2][4][16];
    __shared__ alignas(16) float Ls[4][16];
    __shared__ int Flg[2][4];

    const int tid  = threadIdx.x;
    const int lane = tid & 63;
    const int wv   = tid >> 6;
    const int lr   = lane & 15, lg = lane >> 4;
    const int b    = blockIdx.y;
    const size_t qblk = (size_t)b * SEQ + blockIdx.x * 64;

    // Q frags (B-operand): wave wv owns q-tile wv
    short8 aq[8];
    #pragma unroll
    for (int c = 0; c < 8; ++c)
        aq[c] = *(const short8*)&Q[(qblk + wv * 16 + lr) * 256 + c * 32 + lg * 8];

    float m_run = -1e30f, l_run = 0.f;   // per-lane: q-row = lr (log2 domain)
    f32x4 o[4][4] = {};   // [qt][dt]: rows qt*16+lg*4+r, cols wv*64+dt*16+lr

    const int krow = tid >> 3;           // K staging: row 0..31
    const int kc8  = (tid & 7) * 8;      // chunk element offset (16B chunks)
    const unsigned short* Kb = K + (size_t)b * SEQ * 256;
    const unsigned short* Vb = Vt + ((size_t)b * 256 << 13);
    size_t vrow[4];
    #pragma unroll
    for (int dt = 0; dt < 4; ++dt)
        vrow[dt] = (size_t)(wv * 64 + dt * 16 + lr) << 13;

    // prologue: stage tile 0 into Ks[0] (128B-interleaved chunks)
    {
        const unsigned short* s = &Kb[(size_t)krow * 256 + kc8];
        int4 x0 = *(const int4*)(s);
        int4 x1 = *(const int4*)(s + 64);
        int4 x2 = *(const int4*)(s + 128);
        int4 x3 = *(const int4*)(s + 192);
        *(int4*)&Ks[0][krow][kc8]       = x0;
        *(int4*)&Ks[0][krow][kc8 + 64]  = x1;
        *(int4*)&Ks[0][krow][kc8 + 128] = x2;
        *(int4*)&Ks[0][krow][kc8 + 192] = x3;
    }
    __syncthreads();

    for (int t = 0; t < NT; ++t) {
        const int p = t & 1;
        const bool have = (t + 1 < NT);

        // issue K(t+1) loads early (latency hides under QK)
        int4 x0, x1, x2, x3;
        if (have) {
            const unsigned short* s = &Kb[((size_t)(t + 1) * 32 + krow) * 256 + kc8];
            x0 = *(const int4*)(s);
            x1 = *(const int4*)(s + 64);
            x2 = *(const int4*)(s + 128);
            x3 = *(const int4*)(s + 192);
        }
        // V^T frags for PV(t-1), direct from global (L2-resident)
        short8 vbr[4];
        if (t > 0) {
            const size_t kvp = (size_t)(t - 1) * 32 + lg * 8;
            #pragma unroll
            for (int dt = 0; dt < 4; ++dt)
                vbr[dt] = *(const short8*)&Vb[vrow[dt] + kvp];
        }

        // QK(t) from Ks[p] (swapped): s0 = kv 0..15, s1 = kv 16..31
        f32x4 s0 = {}, s1 = {};
        #pragma unroll
        for (int c = 0; c < 8; ++c) {
            short8 kb0 = *(const short8*)&Ks[p][lr][c * 32 + lg * 8];
            short8 kb1 = *(const short8*)&Ks[p][16 + lr][c * 32 + lg * 8];
            s0 = __builtin_amdgcn_mfma_f32_16x16x32_bf16(kb0, aq[c], s0, 0, 0, 0);
            s1 = __builtin_amdgcn_mfma_f32_16x16x32_bf16(kb1, aq[c], s1, 0, 0, 0);
        }

        // write staged K(t+1) into the other buffer (conflict-free map)
        if (have) {
            *(int4*)&Ks[p ^ 1][krow][kc8]       = x0;
            *(int4*)&Ks[p ^ 1][krow][kc8 + 64]  = x1;
            *(int4*)&Ks[p ^ 1][krow][kc8 + 128] = x2;
            *(int4*)&Ks[p ^ 1][krow][kc8 + 192] = x3;
        }

        // online softmax for q=lr (log2 domain), defer-rescale THR=11
        float mx = fmaxf(fmaxf(fmaxf(s0[0], s0[1]), fmaxf(s0[2], s0[3])),
                         fmaxf(fmaxf(s1[0], s1[1]), fmaxf(s1[2], s1[3])));
        mx = fmaxf(mx, __shfl_xor(mx, 16, 64));
        mx = fmaxf(mx, __shfl_xor(mx, 32, 64));

        const int need = __any(mx > m_run + 11.0f);
        float corr = 1.f;
        if (need) {
            float mnew = fmaxf(m_run, mx);
            corr = exp2f(m_run - mnew);
            m_run = mnew;
            if (lane < 16) Cor[p ^ 1][wv][lr] = corr;
        }
        if (lane == 0) Flg[p ^ 1][wv] = need;

        float p0[4], p1[4];
        #pragma unroll
        for (int r = 0; r < 4; ++r) {
            p0[r] = exp2f(s0[r] - m_run);
            p1[r] = exp2f(s1[r] - m_run);
        }
        float rs = ((p0[0] + p0[1]) + (p0[2] + p0[3])) +
                   ((p1[0] + p1[1]) + (p1[2] + p1[3]));
        rs += __shfl_xor(rs, 16, 64);
        rs += __shfl_xor(rs, 32, 64);
        l_run = (need ? l_run * corr : l_run) + rs;

        {   // pack P -> Ps[p^1] (kv-contiguous per lane), 2x b64
            unsigned int w0 = (unsigned)f2bf(p0[0]) | ((unsigned)f2bf(p0[1]) << 16);
            unsigned int w1 = (unsigned)f2bf(p0[2]) | ((unsigned)f2bf(p0[3]) << 16);
            unsigned int w2 = (unsigned)f2bf(p1[0]) | ((unsigned)f2bf(p1[1]) << 16);
            unsigned int w3 = (unsigned)f2bf(p1[2]) | ((unsigned)f2bf(p1[3]) << 16);
            *(unsigned long long*)&Ps[p ^ 1][wv][lr][4 * lg] =
                (unsigned long long)w0 | ((unsigned long long)w1 << 32);
            *(unsigned long long*)&Ps[p ^ 1][wv][lr][16 + 4 * lg] =
                (unsigned long long)w2 | ((unsigned long long)w3 << 32);
        }

        // PV(t-1): P from Ps[p], rescale via Flg/Cor[p], V frags from global
        if (t > 0) {
            short8 pa[4];
            #pragma unroll
            for (int qt = 0; qt < 4; ++qt)
                pa[qt] = *(const short8*)&Ps[p][qt][lr][lg * 8];
            #pragma unroll
            for (int qt = 0; qt < 4; ++qt) {
                if (Flg[p][qt]) {
                    float4 c4 = *(const float4*)&Cor[p][qt][lg * 4];
                    #pragma unroll
                    for (int dt = 0; dt < 4; ++dt) {
                        o[qt][dt][0] *= c4.x; o[qt][dt][1] *= c4.y;
                        o[qt][dt][2] *= c4.z; o[qt][dt][3] *= c4.w;
                    }
                }
                #pragma unroll
                for (int dt = 0; dt < 4; ++dt)
                    o[qt][dt] = __builtin_amdgcn_mfma_f32_16x16x32_bf16(pa[qt], vbr[dt], o[qt][dt], 0, 0, 0);
            }
        }
        __syncthreads();   // Ks[p^1] + Ps/Cor/Flg[p^1] visible; reads of [p] done
    }

    // epilogue: PV(NT-1) from Ps[NT&1]
    {
        const int p = NT & 1;
        const size_t kvp = (size_t)(NT - 1) * 32 + lg * 8;
        short8 vbr[4];
        #pragma unroll
        for (int dt = 0; dt < 4; ++dt)
            vbr[dt] = *(const short8*)&Vb[vrow[dt] + kvp];
        short8 pa[4];
        #pragma unroll
        for (int qt = 0; qt < 4; ++qt)
            pa[qt] = *(const short8*)&Ps[p][qt][lr][lg * 8];
        #pragma unroll
        for (int qt = 0; qt < 4; ++qt) {
            if (Flg[p][qt]) {
                float4 c4 = *(const float4*)&Cor[p][qt][lg * 4];
                #pragma unroll
                for (int dt = 0; dt < 4; ++dt) {
                    o[qt][dt][0] *= c4.x; o[qt][dt][1] *= c4.y;
                    o[qt][dt][2] *= c4.z; o[qt][dt][3] *= c4.w;
                }
            }
            #pragma unroll
            for (int dt = 0; dt < 4; ++dt)
                o[qt][dt] = __builtin_amdgcn_mfma_f32_16x16x32_bf16(pa[qt], vbr[dt], o[qt][dt], 0, 0, 0);
        }
    }

    // broadcast l, normalize, write
    if (lane < 16) Ls[wv][lr] = l_run;
    __syncthreads();
    #pragma unroll
    for (int qt = 0; qt < 4; ++qt) {
        float4 l4 = *(const float4*)&Ls[qt][lg * 4];
        float inv[4] = {1.f / l4.x, 1.f / l4.y, 1.f / l4.z, 1.f / l4.w};
        #pragma unroll
        for (int dt = 0; dt < 4; ++dt)
            #pragma unroll
            for (int r = 0; r < 4; ++r)
                A[(qblk + qt * 16 + lg * 4 + r) * 256 + wv * 64 + dt * 16 + lr] =
                    f2bf(o[qt][dt][r] * inv[r]);
    }
}

extern "C" void kernel_launch(void* const* d_in, const int* in_sizes, int n_in,
                              void* d_out, int out_size, void* d_ws, size_t ws_size,
                              hipStream_t stream) {
    (void)in_sizes; (void)n_in; (void)out_size; (void)ws_size;
    const float* x  = (const float*)d_in[0];
    const float* Wq = (const float*)d_in[1];
    const float* bq = (const float*)d_in[2];
    const float* Wk = (const float*)d_in[3];
    const float* bk = (const float*)d_in[4];
    const float* Wv = (const float*)d_in[5];
    const float* bv = (const float*)d_in[6];
    const float* Wo = (const float*)d_in[7];
    const float* bo = (const float*)d_in[8];
    float* out = (float*)d_out;

    char* ws = (char*)d_ws;
    const size_t MB16 = (size_t)16 * 1024 * 1024;
    unsigned short* qb = (unsigned short*)(ws);
    unsigned short* kb = (unsigned short*)(ws + MB16);
    unsigned short* vt = (unsigned short*)(ws + 2 * MB16);  // V^T [b][d][S]
    unsigned short* ab = (unsigned short*)(ws + 3 * MB16);

    dim3 gg(256, 2), bb(256);
    // scores in log2 domain: Q scale = d^-0.5 * log2(e)
    proj_gemm<false, 0><<<gg, bb, 0, stream>>>(x, Wq, bq, qb, 0.0625f * 1.44269504f);
    proj_gemm<false, 0><<<gg, bb, 0, stream>>>(x, Wk, bk, kb, 1.0f);
    proj_gemm<false, 2><<<gg, bb, 0, stream>>>(x, Wv, bv, vt, 1.0f);
    attn_kernel<<<dim3(128, NBATCH), bb, 0, stream>>>(qb, kb, vt, ab);
    proj_gemm<true, 1><<<gg, bb, 0, stream>>>(ab, Wo, bo, out, 1.0f);
}